// Round 15
// baseline (3007.013 us; speedup 1.0000x reference)
//
#include <hip/hip_runtime.h>
#include <cmath>

// ---------------------------------------------------------------------------
// DiffAttn ViT forward on MI355X (gfx950). Round 14: non-GEMM memory-path
// fixes on top of R14's 2920us config:
//  - prep_weights: float4 loads + u16x4 stores (was scalar), tile pad ->68
//    for 8B-aligned vector LDS writes.
//  - diff_attn: K/V staging distributed across all 256 threads (was tid<197).
// GEMM configs unchanged (n64 family at high block counts, ~435-445 TF).
// ---------------------------------------------------------------------------

typedef unsigned short u16;
typedef u16 u16x4 __attribute__((ext_vector_type(4)));
typedef u16 u16x8 __attribute__((ext_vector_type(8)));
typedef float fx4 __attribute__((ext_vector_type(4)));
typedef __bf16 bf16x8 __attribute__((ext_vector_type(8)));

#define MROWS 6304   // B*N = 32*197
#define MPAD  6400

#define WAITV(N) asm volatile("s_waitcnt vmcnt(" #N ")" ::: "memory")

__device__ __forceinline__ float bf2f(u16 u) {
  union { unsigned int i; float f; } c; c.i = ((unsigned int)u) << 16; return c.f;
}
__device__ __forceinline__ u16 f2bf(float f) {
  union { float f; unsigned int i; } c; c.f = f;
  return (u16)((c.i + 0x7FFFu + ((c.i >> 16) & 1u)) >> 16);
}
__device__ __forceinline__ float gelu_f(float x) {
  float u = 0.7978845608028654f * (x + 0.044715f * x * x * x);
  u = fminf(fmaxf(u, -30.f), 30.f);
  float e = __expf(2.f * u);
  return 0.5f * x * (1.f + (e - 1.f) / (e + 1.f));
}

__device__ __forceinline__ void gload16(const void* g, void* l) {
  __builtin_amdgcn_global_load_lds(
      (const __attribute__((address_space(1))) void*)g,
      (__attribute__((address_space(3))) void*)l, 16, 0, 0);
}

// bijective XCD swizzle (m204)
__device__ __forceinline__ int xcd_swz(int orig, int nwg) {
  int q = nwg >> 3, r = nwg & 7;
  int x = orig & 7, i = orig >> 3;
  return (x < r ? x * (q + 1) : r * (q + 1) + (x - r) * q) + i;
}

enum { EP_F32 = 0, EP_BF16 = 1, EP_GELU_BF16 = 2, EP_RESID_F32 = 3 };

template<int MODE>
__device__ __forceinline__ void ep_store(void* outp, const float* __restrict__ resid,
                                         size_t m, size_t n, size_t N, float v) {
  if (MODE == EP_GELU_BF16)      ((u16*)outp)[m * N + n] = f2bf(gelu_f(v));
  else if (MODE == EP_BF16)      ((u16*)outp)[m * N + n] = f2bf(v);
  else if (MODE == EP_RESID_F32) ((float*)outp)[m * N + n] = resid[m * N + n] + v;
  else                           ((float*)outp)[m * N + n] = v;
}

// ---------------------------------------------------------------------------
// SMALL-N GEMM body: 128x64 tile, BK=64, 4 waves, 2-phase dbuf (STATIC 48KB,
// 3 blocks/CU), counted-vmcnt(6). Session-best family.
// ---------------------------------------------------------------------------
template<int MODE, bool BIAS>
__device__ __forceinline__
void gemm_n64_body(const u16* __restrict__ A, const u16* __restrict__ Bt,
                   const float* __restrict__ bias, const float* __restrict__ resid,
                   void* __restrict__ outp, int M, int N, int K, int NT)
{
  __shared__ unsigned char lds[2][(128 + 64) * 64 * 2];  // 48 KB
  const int tid = threadIdx.x;
  const int lane = tid & 63, w = tid >> 6;
  const int g = lane >> 4, l = lane & 15;
  const int wg = xcd_swz(blockIdx.x, gridDim.x);
  const int bm = (wg / NT) * 128, bn = (wg % NT) * 64;

  const int swz_half = ((lane & 7) ^ ((lane >> 3) & 7)) << 3;
  const u16* gA = A + (size_t)(bm + 32 * w + (lane >> 3)) * K + swz_half;
  const u16* gB = Bt + (size_t)(bn + 16 * w + (lane >> 3)) * K + swz_half;

  fx4 acc[2][4] = {};

  auto STAGE = [&](int buf, int kt) {
    unsigned char* bA = &lds[buf][0] + 4096 * w;
    unsigned char* bB = &lds[buf][0] + 16384 + 2048 * w;
    #pragma unroll
    for (int c = 0; c < 4; ++c)
      gload16(gA + (size_t)(8 * c) * K + kt, bA + (8 * c) * 128);
    #pragma unroll
    for (int c = 0; c < 2; ++c)
      gload16(gB + (size_t)(8 * c) * K + kt, bB + (8 * c) * 128);
  };

  STAGE(0, 0);
  int cur = 0;
  for (int kt = 0; kt < K; kt += 64) {
    if (kt + 64 < K) {
      STAGE(cur ^ 1, kt + 64);
      WAITV(6);
    } else {
      WAITV(0);
    }
    __builtin_amdgcn_s_barrier();
    __builtin_amdgcn_sched_barrier(0);
    const unsigned char* As = &lds[cur][0];
    const unsigned char* Bs = As + 16384;
    #pragma unroll
    for (int kk = 0; kk < 2; ++kk) {
      bf16x8 af[2], bfr[4];
      #pragma unroll
      for (int i = 0; i < 2; ++i) {
        int ar = w * 32 + i * 16 + l;
        af[i] = *(const bf16x8*)(As + ar * 128 + ((kk * 64 + g * 16) ^ ((ar & 7) << 4)));
      }
      #pragma unroll
      for (int j = 0; j < 4; ++j) {
        int br = j * 16 + l;
        bfr[j] = *(const bf16x8*)(Bs + br * 128 + ((kk * 64 + g * 16) ^ ((br & 7) << 4)));
      }
      #pragma unroll
      for (int i = 0; i < 2; ++i)
        #pragma unroll
        for (int j = 0; j < 4; ++j)
          acc[i][j] = __builtin_amdgcn_mfma_f32_16x16x32_bf16(af[i], bfr[j], acc[i][j], 0, 0, 0);
    }
    __builtin_amdgcn_sched_barrier(0);
    __builtin_amdgcn_s_barrier();
    cur ^= 1;
  }
  #pragma unroll
  for (int j = 0; j < 4; ++j) {
    int n = bn + j * 16 + l;
    float bv = BIAS ? bias[n] : 0.f;
    #pragma unroll
    for (int i = 0; i < 2; ++i) {
      int mbase = bm + w * 32 + i * 16 + g * 4;
      #pragma unroll
      for (int q = 0; q < 4; ++q) {
        int m = mbase + q;
        if (m < M) ep_store<MODE>(outp, resid, m, n, N, acc[i][j][q] + bv);
      }
    }
  }
}

// ---- kernel symbols ----
__global__ __launch_bounds__(256) void patch_gemm(const u16* A, const u16* Bt, float* outp) {
  gemm_n64_body<EP_F32, false>(A, Bt, nullptr, nullptr, outp, 6272, 768, 768, 12);
}
__global__ __launch_bounds__(256) void qkv_gemm(const u16* A, const u16* Bt, u16* outp) {
  gemm_n64_body<EP_BF16, false>(A, Bt, nullptr, nullptr, outp, MROWS, 2304, 768, 36);
}
__global__ __launch_bounds__(256) void oproj_gemm(const u16* A, const u16* Bt,
                                                  const float* resid, float* outp) {
  gemm_n64_body<EP_RESID_F32, false>(A, Bt, nullptr, resid, outp, MROWS, 768, 768, 12);
}
__global__ __launch_bounds__(256) void mlp1_gemm(const u16* A, const u16* Bt,
                                                 const float* bias, u16* outp) {
  gemm_n64_body<EP_GELU_BF16, true>(A, Bt, bias, nullptr, outp, MROWS, 3072, 768, 48);
}
__global__ __launch_bounds__(256) void mlp2_gemm(const u16* A, const u16* Bt,
                                                 const float* bias, const float* resid,
                                                 float* outp) {
  gemm_n64_body<EP_RESID_F32, true>(A, Bt, bias, resid, outp, MROWS, 768, 3072, 12);
}

// 4 rows/block (one wave each); OUTF32 ? f32 out : bf16 out
template<bool OUTF32>
__global__ __launch_bounds__(256)
void layernorm_k(const float* __restrict__ x, const float* __restrict__ s,
                 const float* __restrict__ b, void* __restrict__ outp,
                 int nrows, size_t in_rstride)
{
  int r = blockIdx.x * 4 + (threadIdx.x >> 6);
  if (r >= nrows) return;
  int lane = threadIdx.x & 63;
  const fx4* xp = (const fx4*)(x + (size_t)r * in_rstride);
  fx4 v[3];
  float sum = 0.f, sq = 0.f;
  #pragma unroll
  for (int j = 0; j < 3; ++j) {
    v[j] = xp[j * 64 + lane];
    #pragma unroll
    for (int e = 0; e < 4; ++e) { sum += v[j][e]; sq += v[j][e] * v[j][e]; }
  }
  #pragma unroll
  for (int off = 32; off; off >>= 1) { sum += __shfl_xor(sum, off); sq += __shfl_xor(sq, off); }
  float mu = sum * (1.f / 768.f);
  float var = sq * (1.f / 768.f) - mu * mu;
  float rs = rsqrtf(var + 1e-5f);
  const fx4* sp = (const fx4*)s;
  const fx4* bp = (const fx4*)b;
  #pragma unroll
  for (int j = 0; j < 3; ++j) {
    fx4 sv = sp[j * 64 + lane], bv = bp[j * 64 + lane];
    if (OUTF32) {
      fx4 o;
      #pragma unroll
      for (int e = 0; e < 4; ++e) o[e] = (v[j][e] - mu) * rs * sv[e] + bv[e];
      *(fx4*)((float*)outp + (size_t)r * 768 + (j * 64 + lane) * 4) = o;
    } else {
      u16x4 o;
      #pragma unroll
      for (int e = 0; e < 4; ++e) o[e] = f2bf((v[j][e] - mu) * rs * sv[e] + bv[e]);
      *(u16x4*)((u16*)outp + (size_t)r * 768 + (j * 64 + lane) * 4) = o;
    }
  }
}

// ---------------------------------------------------------------------------
// MFMA differential attention. One block per (batch, value-head, q-half).
// Staging distributed across all 256 threads (R14: was tid<197 only).
// ---------------------------------------------------------------------------
#define KSTR 40
#define VSTR 232
#define DA_LDS (2 * 224 * KSTR * 2 + 64 * VSTR * 2 + 4 * 16 * VSTR * 2)  // 95232 B

__global__ __launch_bounds__(256)
void diff_attn(const u16* __restrict__ qkv, const float* __restrict__ lam_p,
               const float* __restrict__ sls, u16* __restrict__ outp, float lam_init)
{
  extern __shared__ char smem[];
  u16* K1s = (u16*)smem;
  u16* K2s = K1s + 224 * KSTR;
  u16* Vt  = K2s + 224 * KSTR;
  const int tid = threadIdx.x;
  const int w = tid >> 6, lane = tid & 63;
  const int g = lane >> 4, l = lane & 15;
  u16* Pw = Vt + 64 * VSTR + w * 16 * VSTR;

  const int bh = blockIdx.x >> 1;
  const int half = blockIdx.x & 1;
  const int b = bh / 12, hh = bh % 12;
  const u16* base = qkv + (size_t)b * 197 * 2304;

  // K staging: 197 rows x 8 chunks of u16x8 (c<4 -> K1, else K2)
  for (int idx = tid; idx < 197 * 8; idx += 256) {
    int row = idx >> 3, c = idx & 7;
    const u16* kr = base + (size_t)row * 2304 + 768 + hh * 64;
    u16x8 vv = *(const u16x8*)(kr + c * 8);
    if (c < 4) *(u16x8*)(K1s + row * KSTR + c * 8) = vv;
    else       *(u16x8*)(K2s + row * KSTR + (c - 4) * 8) = vv;
  }
  // V transpose staging: 197 rows x 8 chunks, scatter to Vt[dv][m]
  for (int idx = tid; idx < 197 * 8; idx += 256) {
    int m = idx >> 3, c = idx & 7;
    const u16* vr = base + (size_t)m * 2304 + 1536 + hh * 64;
    u16x8 vv = *(const u16x8*)(vr + c * 8);
    #pragma unroll
    for (int e = 0; e < 8; ++e) Vt[(c * 8 + e) * VSTR + m] = vv[e];
  }
  for (int idx = tid; idx < 64 * 27; idx += 256) {
    Vt[(idx / 27) * VSTR + 197 + (idx % 27)] = 0;
  }
  __syncthreads();

  const float lam = lam_p[0];
  const float oscale = 1.f - lam_init;
  const float scale = 0.17677669529663687f;
  const fx4 zero = {};

  const int qb_lo = half ? 7 : 0;
  const int qb_hi = half ? 13 : 7;
  for (int qb = qb_lo + w; qb < qb_hi; qb += 4) {
    const int qbase = qb * 16;
    const u16* qrow = base + (size_t)(qbase + l) * 2304 + hh * 64;
    bf16x8 qf1 = *(const bf16x8*)(qrow + g * 8);
    bf16x8 qf2 = *(const bf16x8*)(qrow + 32 + g * 8);

    fx4 s1[14], s2[14];
    #pragma unroll
    for (int t = 0; t < 14; ++t) {
      bf16x8 kf1 = *(const bf16x8*)(K1s + (t * 16 + l) * KSTR + g * 8);
      bf16x8 kf2 = *(const bf16x8*)(K2s + (t * 16 + l) * KSTR + g * 8);
      s1[t] = __builtin_amdgcn_mfma_f32_16x16x32_bf16(qf1, kf1, zero, 0, 0, 0);
      s2[t] = __builtin_amdgcn_mfma_f32_16x16x32_bf16(qf2, kf2, zero, 0, 0, 0);
    }

    float mx1[4] = {-1e30f, -1e30f, -1e30f, -1e30f};
    float mx2[4] = {-1e30f, -1e30f, -1e30f, -1e30f};
    #pragma unroll
    for (int t = 0; t < 14; ++t) {
      bool ok = (t * 16 + l) < 197;
      #pragma unroll
      for (int q = 0; q < 4; ++q) {
        float v1 = ok ? s1[t][q] * scale : -1e30f;
        float v2 = ok ? s2[t][q] * scale : -1e30f;
        s1[t][q] = v1; s2[t][q] = v2;
        mx1[q] = fmaxf(mx1[q], v1); mx2[q] = fmaxf(mx2[q], v2);
      }
    }
    #pragma unroll
    for (int off = 8; off; off >>= 1)
      #pragma unroll
      for (int q = 0; q < 4; ++q) {
        mx1[q] = fmaxf(mx1[q], __shfl_xor(mx1[q], off));
        mx2[q] = fmaxf(mx2[q], __shfl_xor(mx2[q], off));
      }
    float z1[4] = {0, 0, 0, 0}, z2[4] = {0, 0, 0, 0};
    #pragma unroll
    for (int t = 0; t < 14; ++t)
      #pragma unroll
      for (int q = 0; q < 4; ++q) {
        float p1 = __expf(s1[t][q] - mx1[q]);
        float p2 = __expf(s2[t][q] - mx2[q]);
        s1[t][q] = p1; s2[t][q] = p2;
        z1[q] += p1; z2[q] += p2;
      }
    #pragma unroll
    for (int off = 8; off; off >>= 1)
      #pragma unroll
      for (int q = 0; q < 4; ++q) {
        z1[q] += __shfl_xor(z1[q], off);
        z2[q] += __shfl_xor(z2[q], off);
      }
    float r1[4], r2[4];
    #pragma unroll
    for (int q = 0; q < 4; ++q) { r1[q] = 1.f / z1[q]; r2[q] = lam / z2[q]; }

    #pragma unroll
    for (int t = 0; t < 14; ++t)
      #pragma unroll
      for (int q = 0; q < 4; ++q) {
        float pc = s1[t][q] * r1[q] - s2[t][q] * r2[q];
        Pw[(g * 4 + q) * VSTR + t * 16 + l] = f2bf(pc);
      }

    fx4 o[4] = {};
    #pragma unroll
    for (int mt = 0; mt < 7; ++mt) {
      bf16x8 pa = *(const bf16x8*)(Pw + l * VSTR + mt * 32 + g * 8);
      #pragma unroll
      for (int j = 0; j < 4; ++j) {
        bf16x8 vb = *(const bf16x8*)(Vt + (j * 16 + l) * VSTR + mt * 32 + g * 8);
        o[j] = __builtin_amdgcn_mfma_f32_16x16x32_bf16(pa, vb, o[j], 0, 0, 0);
      }
    }

    float ms[4] = {0, 0, 0, 0};
    #pragma unroll
    for (int j = 0; j < 4; ++j)
      #pragma unroll
      for (int q = 0; q < 4; ++q) ms[q] += o[j][q] * o[j][q];
    #pragma unroll
    for (int off = 8; off; off >>= 1)
      #pragma unroll
      for (int q = 0; q < 4; ++q) ms[q] += __shfl_xor(ms[q], off);
    float rr[4];
    #pragma unroll
    for (int q = 0; q < 4; ++q) rr[q] = rsqrtf(ms[q] * (1.f / 64.f) + 1e-5f) * oscale;
    #pragma unroll
    for (int j = 0; j < 4; ++j) {
      float slv = sls[j * 16 + l];
      #pragma unroll
      for (int q = 0; q < 4; ++q) {
        int row = qbase + g * 4 + q;
        if (row < 197)
          outp[(size_t)(b * 197 + row) * 768 + hh * 64 + j * 16 + l] = f2bf(o[j][q] * rr[q] * slv);
      }
    }
  }
}

// per-layer weight prep: f32 [K][N] -> bf16 [N][K]; vectorized (float4 in,
// u16x4 out); tile pad 68 so rows are 8B-aligned for u16x4 LDS writes.
__global__ __launch_bounds__(256)
void prep_weights(const float* __restrict__ qw, const float* __restrict__ kw,
                  const float* __restrict__ vw, const float* __restrict__ ow,
                  const float* __restrict__ w1, const float* __restrict__ w2,
                  u16* __restrict__ qkvt, u16* __restrict__ ot,
                  u16* __restrict__ w1t, u16* __restrict__ w2t,
                  const float* __restrict__ lq1, const float* __restrict__ lk1,
                  const float* __restrict__ lq2, const float* __restrict__ lk2,
                  float* __restrict__ lam_out, float lam_init)
{
  int bid = blockIdx.x;
  if (bid == 1728) {
    if (threadIdx.x < 64) {
      int lane = threadIdx.x;
      float p1 = lane < 32 ? lq1[lane] * lk1[lane] : 0.f;
      float p2 = lane < 32 ? lq2[lane] * lk2[lane] : 0.f;
      #pragma unroll
      for (int off = 32; off; off >>= 1) { p1 += __shfl_xor(p1, off); p2 += __shfl_xor(p2, off); }
      if (lane == 0) lam_out[0] = __expf(p1) - __expf(p2) + lam_init;
    }
    return;
  }
  const float* src; u16* dst; int Kd, Nd, tx, ty;
  if (bid < 576) {
    int which = bid / 144, t = bid % 144;
    ty = t / 12; tx = t % 12; Kd = 768; Nd = 768;
    src = (which == 0) ? qw : (which == 1) ? kw : (which == 2) ? vw : ow;
    dst = (which < 3) ? (qkvt + (size_t)which * 768 * 768) : ot;
  } else if (bid < 1152) {
    int t = bid - 576; ty = t / 12; tx = t % 12; Kd = 768; Nd = 3072; src = w1; dst = w1t;
  } else {
    int t = bid - 1152; ty = t / 48; tx = t % 48; Kd = 3072; Nd = 768; src = w2; dst = w2t;
  }
  __shared__ u16 tile[64][68];
  int tid2 = threadIdx.x;
  int k0 = tx * 64, n0 = ty * 64;
  #pragma unroll
  for (int j = 0; j < 4; ++j) {
    int idx = j * 256 + tid2;
    int rr = idx >> 4, c4 = idx & 15;
    fx4 v = *(const fx4*)(src + (size_t)(k0 + rr) * Nd + n0 + c4 * 4);
    u16x4 o;
    #pragma unroll
    for (int e = 0; e < 4; ++e) o[e] = f2bf(v[e]);
    *(u16x4*)&tile[rr][c4 * 4] = o;
  }
  __syncthreads();
  #pragma unroll
  for (int j = 0; j < 4; ++j) {
    int idx = j * 256 + tid2;
    int rr = idx >> 4, c4 = idx & 15;
    u16x4 o;
    #pragma unroll
    for (int e = 0; e < 4; ++e) o[e] = tile[c4 * 4 + e][rr];
    *(u16x4*)(dst + (size_t)(n0 + rr) * Kd + k0 + c4 * 4) = o;
  }
}

__global__ void convert_cw(const float* __restrict__ src, u16* __restrict__ dst)
{
  int i4 = blockIdx.x * 256 + threadIdx.x;
  fx4 v = *(const fx4*)(src + (size_t)i4 * 4);
  u16x4 o;
  #pragma unroll
  for (int e = 0; e < 4; ++e) o[e] = f2bf(v[e]);
  *(u16x4*)(dst + (size_t)i4 * 4) = o;
}

__global__ void im2col(const float* __restrict__ x, u16* __restrict__ A0)
{
  int i4 = blockIdx.x * 256 + threadIdx.x;
  int base = i4 * 4;
  int r = base / 768, c0 = base % 768;
  int b = r / 196, p = r % 196;
  int py = p / 14, px = p % 14;
  int ch = c0 >> 8;
  int cc = c0 & 255;
  int iy = cc >> 4, ix = cc & 15;
  const float* src = x + (((size_t)(b * 3 + ch) * 224 + py * 16 + iy) * 224 + px * 16 + ix);
  fx4 v = *(const fx4*)src;
  u16x4 o;
  #pragma unroll
  for (int e = 0; e < 4; ++e) o[e] = f2bf(v[e]);
  *(u16x4*)(A0 + base) = o;
}

__global__ void assemble(const float* __restrict__ tmp, const float* __restrict__ conv_b,
                         const float* __restrict__ cls, const float* __restrict__ pos,
                         float* __restrict__ h)
{
  int i4 = blockIdx.x * 256 + threadIdx.x;
  int base = i4 * 4;
  int r = base / 768, d = base % 768;
  int b = r / 197, n = r % 197;
  fx4 pv = *(const fx4*)(pos + (size_t)n * 768 + d);
  fx4 v;
  if (n == 0) {
    v = *(const fx4*)(cls + d);
  } else {
    v = *(const fx4*)(tmp + (size_t)(b * 196 + n - 1) * 768 + d);
    fx4 cb = *(const fx4*)(conv_b + d);
    v = v + cb;
  }
  *(fx4*)(h + (size_t)r * 768 + d) = v + pv;
}

__global__ __launch_bounds__(256)
void head_kernel(const float* __restrict__ ln, const float* __restrict__ hw,
                 const float* __restrict__ hb, float* __restrict__ outp)
{
  int r = blockIdx.x;
  int c = blockIdx.y * 256 + threadIdx.x;
  if (c >= 1000) return;
  const float* lr = ln + (size_t)r * 768;
  float acc = hb[c];
  for (int d = 0; d < 768; ++d)
    acc = fmaf(lr[d], hw[(size_t)d * 1000 + c], acc);
  outp[r * 1000 + c] = acc;
}

extern "C" void kernel_launch(void* const* d_in, const int* in_sizes, int n_in,
                              void* d_out, int out_size, void* d_ws, size_t ws_size,
                              hipStream_t stream)
{
  (void)in_sizes; (void)n_in; (void)out_size; (void)ws_size;
  const float* x      = (const float*)d_in[0];
  const float* conv_w = (const float*)d_in[1];
  const float* conv_b = (const float*)d_in[2];
  const float* cls    = (const float*)d_in[3];
  const float* pos    = (const float*)d_in[4];
  const float* ln1_s  = (const float*)d_in[5];
  const float* ln1_b  = (const float*)d_in[6];
  const float* q_w    = (const float*)d_in[7];
  const float* k_w    = (const float*)d_in[8];
  const float* v_w    = (const float*)d_in[9];
  const float* o_w    = (const float*)d_in[10];
  const float* lq1    = (const float*)d_in[11];
  const float* lk1    = (const float*)d_in[12];
  const float* lq2    = (const float*)d_in[13];
  const float* lk2    = (const float*)d_in[14];
  const float* slsx   = (const float*)d_in[15];
  const float* ln2_s  = (const float*)d_in[16];
  const float* ln2_b  = (const float*)d_in[17];
  const float* w1     = (const float*)d_in[18];
  const float* b1     = (const float*)d_in[19];
  const float* w2     = (const float*)d_in[20];
  const float* b2     = (const float*)d_in[21];
  const float* lnf_s  = (const float*)d_in[22];
  const float* lnf_b  = (const float*)d_in[23];
  const float* head_w = (const float*)d_in[24];
  const float* head_b = (const float*)d_in[25];
  float* out = (float*)d_out;

  char* ws = (char*)d_ws;
  size_t off = 0;
  auto alloc = [&](size_t bytes) { size_t p = off; off += (bytes + 255) & ~(size_t)255; return p; };
  u16*   A_bf  = (u16*)  (ws + alloc((size_t)MPAD * 768 * 2));
  u16*   big   = (u16*)  (ws + alloc((size_t)MPAD * 3072 * 2));
  float* h     = (float*)(ws + alloc((size_t)MROWS * 768 * 4));
  u16*   wqkv  = (u16*)  (ws + alloc((size_t)2304 * 768 * 2));
  u16*   wo    = (u16*)  (ws + alloc((size_t)768 * 768 * 2));
  u16*   w1t   = (u16*)  (ws + alloc((size_t)3072 * 768 * 2));
  u16*   w2t   = (u16*)  (ws + alloc((size_t)768 * 3072 * 2));
  float* lnf_o = (float*)(ws + alloc((size_t)32 * 768 * 4));
  float* lam   = (float*)(ws + alloc(256));
  float* convtmp = (float*)big;
  u16*   cwbf  = w1t;

  hipFuncSetAttribute((const void*)diff_attn,
                      hipFuncAttributeMaxDynamicSharedMemorySize, DA_LDS);

  // patch embed
  convert_cw<<<576, 256, 0, stream>>>(conv_w, cwbf);
  im2col<<<4704, 256, 0, stream>>>(x, A_bf);
  patch_gemm<<<588, 256, 0, stream>>>(A_bf, cwbf, convtmp);   // 49 * 12
  assemble<<<4728, 256, 0, stream>>>(convtmp, conv_b, cls, pos, h);

  for (int l = 0; l < 12; ++l) {
    float lam_init = 0.8f - 0.6f * expf(-0.3f * (float)l);
    prep_weights<<<1729, 256, 0, stream>>>(
        q_w + (size_t)l * 589824, k_w + (size_t)l * 589824,
        v_w + (size_t)l * 589824, o_w + (size_t)l * 589824,
        w1 + (size_t)l * 2359296, w2 + (size_t)l * 2359296,
        wqkv, wo, w1t, w2t,
        lq1 + l * 32, lk1 + l * 32, lq2 + l * 32, lk2 + l * 32,
        lam, lam_init);
    layernorm_k<false><<<1576, 256, 0, stream>>>(h, ln1_s + l * 768, ln1_b + l * 768, A_bf, MROWS, (size_t)768);
    qkv_gemm<<<1800, 256, 0, stream>>>(A_bf, wqkv, big);                 // 50 * 36 n64
    diff_attn<<<768, 256, DA_LDS, stream>>>(big, lam, slsx + l * 64, A_bf, lam_init);
    oproj_gemm<<<600, 256, 0, stream>>>(A_bf, wo, h, h);                 // 50 * 12
    layernorm_k<false><<<1576, 256, 0, stream>>>(h, ln2_s + l * 768, ln2_b + l * 768, A_bf, MROWS, (size_t)768);
    mlp1_gemm<<<2400, 256, 0, stream>>>(A_bf, w1t, b1 + l * 3072, big);  // 50 * 48 n64
    mlp2_gemm<<<600, 256, 0, stream>>>(big, w2t, b2 + l * 768, h, h);    // 50 * 12
  }

  layernorm_k<true><<<8, 256, 0, stream>>>(h, lnf_s, lnf_b, lnf_o, 32, (size_t)197 * 768);
  head_kernel<<<dim3(32, 4), 256, 0, stream>>>(lnf_o, head_w, head_b, out);
}

// Round 16
// 2886.621 us; speedup vs baseline: 1.0417x; 1.0417x over previous
//
#include <hip/hip_runtime.h>
#include <cmath>

// ---------------------------------------------------------------------------
// DiffAttn ViT forward on MI355X (gfx950). Round 15:
//  - REVERT R15's prep_weights + diff_attn staging edits (2920 -> 3007
//    regression; post-mortem matrix says revert on didn't-match+hurt).
//  - head_kernel rewritten: grid (32,16), 4-wave d-split (192/wave) + LDS
//    reduce. Was 67us latency-bound (128 blocks, 768-deep serial chain).
// Everything else = R14 measured optimum (2920us).
// ---------------------------------------------------------------------------

typedef unsigned short u16;
typedef u16 u16x4 __attribute__((ext_vector_type(4)));
typedef u16 u16x8 __attribute__((ext_vector_type(8)));
typedef float fx4 __attribute__((ext_vector_type(4)));
typedef __bf16 bf16x8 __attribute__((ext_vector_type(8)));

#define MROWS 6304   // B*N = 32*197
#define MPAD  6400

#define WAITV(N) asm volatile("s_waitcnt vmcnt(" #N ")" ::: "memory")

__device__ __forceinline__ float bf2f(u16 u) {
  union { unsigned int i; float f; } c; c.i = ((unsigned int)u) << 16; return c.f;
}
__device__ __forceinline__ u16 f2bf(float f) {
  union { float f; unsigned int i; } c; c.f = f;
  return (u16)((c.i + 0x7FFFu + ((c.i >> 16) & 1u)) >> 16);
}
__device__ __forceinline__ float gelu_f(float x) {
  float u = 0.7978845608028654f * (x + 0.044715f * x * x * x);
  u = fminf(fmaxf(u, -30.f), 30.f);
  float e = __expf(2.f * u);
  return 0.5f * x * (1.f + (e - 1.f) / (e + 1.f));
}

__device__ __forceinline__ void gload16(const void* g, void* l) {
  __builtin_amdgcn_global_load_lds(
      (const __attribute__((address_space(1))) void*)g,
      (__attribute__((address_space(3))) void*)l, 16, 0, 0);
}

// bijective XCD swizzle (m204)
__device__ __forceinline__ int xcd_swz(int orig, int nwg) {
  int q = nwg >> 3, r = nwg & 7;
  int x = orig & 7, i = orig >> 3;
  return (x < r ? x * (q + 1) : r * (q + 1) + (x - r) * q) + i;
}

enum { EP_F32 = 0, EP_BF16 = 1, EP_GELU_BF16 = 2, EP_RESID_F32 = 3 };

template<int MODE>
__device__ __forceinline__ void ep_store(void* outp, const float* __restrict__ resid,
                                         size_t m, size_t n, size_t N, float v) {
  if (MODE == EP_GELU_BF16)      ((u16*)outp)[m * N + n] = f2bf(gelu_f(v));
  else if (MODE == EP_BF16)      ((u16*)outp)[m * N + n] = f2bf(v);
  else if (MODE == EP_RESID_F32) ((float*)outp)[m * N + n] = resid[m * N + n] + v;
  else                           ((float*)outp)[m * N + n] = v;
}

// ---------------------------------------------------------------------------
// SMALL-N GEMM body: 128x64 tile, BK=64, 4 waves, 2-phase dbuf (STATIC 48KB,
// 3 blocks/CU), counted-vmcnt(6). Session-best family.
// ---------------------------------------------------------------------------
template<int MODE, bool BIAS>
__device__ __forceinline__
void gemm_n64_body(const u16* __restrict__ A, const u16* __restrict__ Bt,
                   const float* __restrict__ bias, const float* __restrict__ resid,
                   void* __restrict__ outp, int M, int N, int K, int NT)
{
  __shared__ unsigned char lds[2][(128 + 64) * 64 * 2];  // 48 KB
  const int tid = threadIdx.x;
  const int lane = tid & 63, w = tid >> 6;
  const int g = lane >> 4, l = lane & 15;
  const int wg = xcd_swz(blockIdx.x, gridDim.x);
  const int bm = (wg / NT) * 128, bn = (wg % NT) * 64;

  const int swz_half = ((lane & 7) ^ ((lane >> 3) & 7)) << 3;
  const u16* gA = A + (size_t)(bm + 32 * w + (lane >> 3)) * K + swz_half;
  const u16* gB = Bt + (size_t)(bn + 16 * w + (lane >> 3)) * K + swz_half;

  fx4 acc[2][4] = {};

  auto STAGE = [&](int buf, int kt) {
    unsigned char* bA = &lds[buf][0] + 4096 * w;
    unsigned char* bB = &lds[buf][0] + 16384 + 2048 * w;
    #pragma unroll
    for (int c = 0; c < 4; ++c)
      gload16(gA + (size_t)(8 * c) * K + kt, bA + (8 * c) * 128);
    #pragma unroll
    for (int c = 0; c < 2; ++c)
      gload16(gB + (size_t)(8 * c) * K + kt, bB + (8 * c) * 128);
  };

  STAGE(0, 0);
  int cur = 0;
  for (int kt = 0; kt < K; kt += 64) {
    if (kt + 64 < K) {
      STAGE(cur ^ 1, kt + 64);
      WAITV(6);
    } else {
      WAITV(0);
    }
    __builtin_amdgcn_s_barrier();
    __builtin_amdgcn_sched_barrier(0);
    const unsigned char* As = &lds[cur][0];
    const unsigned char* Bs = As + 16384;
    #pragma unroll
    for (int kk = 0; kk < 2; ++kk) {
      bf16x8 af[2], bfr[4];
      #pragma unroll
      for (int i = 0; i < 2; ++i) {
        int ar = w * 32 + i * 16 + l;
        af[i] = *(const bf16x8*)(As + ar * 128 + ((kk * 64 + g * 16) ^ ((ar & 7) << 4)));
      }
      #pragma unroll
      for (int j = 0; j < 4; ++j) {
        int br = j * 16 + l;
        bfr[j] = *(const bf16x8*)(Bs + br * 128 + ((kk * 64 + g * 16) ^ ((br & 7) << 4)));
      }
      #pragma unroll
      for (int i = 0; i < 2; ++i)
        #pragma unroll
        for (int j = 0; j < 4; ++j)
          acc[i][j] = __builtin_amdgcn_mfma_f32_16x16x32_bf16(af[i], bfr[j], acc[i][j], 0, 0, 0);
    }
    __builtin_amdgcn_sched_barrier(0);
    __builtin_amdgcn_s_barrier();
    cur ^= 1;
  }
  #pragma unroll
  for (int j = 0; j < 4; ++j) {
    int n = bn + j * 16 + l;
    float bv = BIAS ? bias[n] : 0.f;
    #pragma unroll
    for (int i = 0; i < 2; ++i) {
      int mbase = bm + w * 32 + i * 16 + g * 4;
      #pragma unroll
      for (int q = 0; q < 4; ++q) {
        int m = mbase + q;
        if (m < M) ep_store<MODE>(outp, resid, m, n, N, acc[i][j][q] + bv);
      }
    }
  }
}

// ---- kernel symbols ----
__global__ __launch_bounds__(256) void patch_gemm(const u16* A, const u16* Bt, float* outp) {
  gemm_n64_body<EP_F32, false>(A, Bt, nullptr, nullptr, outp, 6272, 768, 768, 12);
}
__global__ __launch_bounds__(256) void qkv_gemm(const u16* A, const u16* Bt, u16* outp) {
  gemm_n64_body<EP_BF16, false>(A, Bt, nullptr, nullptr, outp, MROWS, 2304, 768, 36);
}
__global__ __launch_bounds__(256) void oproj_gemm(const u16* A, const u16* Bt,
                                                  const float* resid, float* outp) {
  gemm_n64_body<EP_RESID_F32, false>(A, Bt, nullptr, resid, outp, MROWS, 768, 768, 12);
}
__global__ __launch_bounds__(256) void mlp1_gemm(const u16* A, const u16* Bt,
                                                 const float* bias, u16* outp) {
  gemm_n64_body<EP_GELU_BF16, true>(A, Bt, bias, nullptr, outp, MROWS, 3072, 768, 48);
}
__global__ __launch_bounds__(256) void mlp2_gemm(const u16* A, const u16* Bt,
                                                 const float* bias, const float* resid,
                                                 float* outp) {
  gemm_n64_body<EP_RESID_F32, true>(A, Bt, bias, resid, outp, MROWS, 768, 3072, 12);
}

// 4 rows/block (one wave each); OUTF32 ? f32 out : bf16 out
template<bool OUTF32>
__global__ __launch_bounds__(256)
void layernorm_k(const float* __restrict__ x, const float* __restrict__ s,
                 const float* __restrict__ b, void* __restrict__ outp,
                 int nrows, size_t in_rstride)
{
  int r = blockIdx.x * 4 + (threadIdx.x >> 6);
  if (r >= nrows) return;
  int lane = threadIdx.x & 63;
  const fx4* xp = (const fx4*)(x + (size_t)r * in_rstride);
  fx4 v[3];
  float sum = 0.f, sq = 0.f;
  #pragma unroll
  for (int j = 0; j < 3; ++j) {
    v[j] = xp[j * 64 + lane];
    #pragma unroll
    for (int e = 0; e < 4; ++e) { sum += v[j][e]; sq += v[j][e] * v[j][e]; }
  }
  #pragma unroll
  for (int off = 32; off; off >>= 1) { sum += __shfl_xor(sum, off); sq += __shfl_xor(sq, off); }
  float mu = sum * (1.f / 768.f);
  float var = sq * (1.f / 768.f) - mu * mu;
  float rs = rsqrtf(var + 1e-5f);
  const fx4* sp = (const fx4*)s;
  const fx4* bp = (const fx4*)b;
  #pragma unroll
  for (int j = 0; j < 3; ++j) {
    fx4 sv = sp[j * 64 + lane], bv = bp[j * 64 + lane];
    if (OUTF32) {
      fx4 o;
      #pragma unroll
      for (int e = 0; e < 4; ++e) o[e] = (v[j][e] - mu) * rs * sv[e] + bv[e];
      *(fx4*)((float*)outp + (size_t)r * 768 + (j * 64 + lane) * 4) = o;
    } else {
      u16x4 o;
      #pragma unroll
      for (int e = 0; e < 4; ++e) o[e] = f2bf((v[j][e] - mu) * rs * sv[e] + bv[e]);
      *(u16x4*)((u16*)outp + (size_t)r * 768 + (j * 64 + lane) * 4) = o;
    }
  }
}

// ---------------------------------------------------------------------------
// MFMA differential attention. One block per (batch, value-head, q-half).
// R14 staging (tid<197 row-per-thread) -- the measured-best version.
// ---------------------------------------------------------------------------
#define KSTR 40
#define VSTR 232
#define DA_LDS (2 * 224 * KSTR * 2 + 64 * VSTR * 2 + 4 * 16 * VSTR * 2)  // 95232 B

__global__ __launch_bounds__(256)
void diff_attn(const u16* __restrict__ qkv, const float* __restrict__ lam_p,
               const float* __restrict__ sls, u16* __restrict__ outp, float lam_init)
{
  extern __shared__ char smem[];
  u16* K1s = (u16*)smem;
  u16* K2s = K1s + 224 * KSTR;
  u16* Vt  = K2s + 224 * KSTR;
  const int tid = threadIdx.x;
  const int w = tid >> 6, lane = tid & 63;
  const int g = lane >> 4, l = lane & 15;
  u16* Pw = Vt + 64 * VSTR + w * 16 * VSTR;

  const int bh = blockIdx.x >> 1;
  const int half = blockIdx.x & 1;
  const int b = bh / 12, hh = bh % 12;
  const u16* base = qkv + (size_t)b * 197 * 2304;

  if (tid < 197) {
    const u16* kr = base + (size_t)tid * 2304 + 768 + hh * 64;
    *(u16x8*)(K1s + tid * KSTR + 0)  = *(const u16x8*)(kr + 0);
    *(u16x8*)(K1s + tid * KSTR + 8)  = *(const u16x8*)(kr + 8);
    *(u16x8*)(K1s + tid * KSTR + 16) = *(const u16x8*)(kr + 16);
    *(u16x8*)(K1s + tid * KSTR + 24) = *(const u16x8*)(kr + 24);
    *(u16x8*)(K2s + tid * KSTR + 0)  = *(const u16x8*)(kr + 32);
    *(u16x8*)(K2s + tid * KSTR + 8)  = *(const u16x8*)(kr + 40);
    *(u16x8*)(K2s + tid * KSTR + 16) = *(const u16x8*)(kr + 48);
    *(u16x8*)(K2s + tid * KSTR + 24) = *(const u16x8*)(kr + 56);
    const u16* vr = base + (size_t)tid * 2304 + 1536 + hh * 64;
    #pragma unroll
    for (int jj = 0; jj < 8; ++jj) {
      u16x8 vv = *(const u16x8*)(vr + jj * 8);
      #pragma unroll
      for (int e = 0; e < 8; ++e) Vt[(jj * 8 + e) * VSTR + tid] = vv[e];
    }
  }
  for (int idx = tid; idx < 64 * 27; idx += 256) {
    Vt[(idx / 27) * VSTR + 197 + (idx % 27)] = 0;
  }
  __syncthreads();

  const float lam = lam_p[0];
  const float oscale = 1.f - lam_init;
  const float scale = 0.17677669529663687f;
  const fx4 zero = {};

  const int qb_lo = half ? 7 : 0;
  const int qb_hi = half ? 13 : 7;
  for (int qb = qb_lo + w; qb < qb_hi; qb += 4) {
    const int qbase = qb * 16;
    const u16* qrow = base + (size_t)(qbase + l) * 2304 + hh * 64;
    bf16x8 qf1 = *(const bf16x8*)(qrow + g * 8);
    bf16x8 qf2 = *(const bf16x8*)(qrow + 32 + g * 8);

    fx4 s1[14], s2[14];
    #pragma unroll
    for (int t = 0; t < 14; ++t) {
      bf16x8 kf1 = *(const bf16x8*)(K1s + (t * 16 + l) * KSTR + g * 8);
      bf16x8 kf2 = *(const bf16x8*)(K2s + (t * 16 + l) * KSTR + g * 8);
      s1[t] = __builtin_amdgcn_mfma_f32_16x16x32_bf16(qf1, kf1, zero, 0, 0, 0);
      s2[t] = __builtin_amdgcn_mfma_f32_16x16x32_bf16(qf2, kf2, zero, 0, 0, 0);
    }

    float mx1[4] = {-1e30f, -1e30f, -1e30f, -1e30f};
    float mx2[4] = {-1e30f, -1e30f, -1e30f, -1e30f};
    #pragma unroll
    for (int t = 0; t < 14; ++t) {
      bool ok = (t * 16 + l) < 197;
      #pragma unroll
      for (int q = 0; q < 4; ++q) {
        float v1 = ok ? s1[t][q] * scale : -1e30f;
        float v2 = ok ? s2[t][q] * scale : -1e30f;
        s1[t][q] = v1; s2[t][q] = v2;
        mx1[q] = fmaxf(mx1[q], v1); mx2[q] = fmaxf(mx2[q], v2);
      }
    }
    #pragma unroll
    for (int off = 8; off; off >>= 1)
      #pragma unroll
      for (int q = 0; q < 4; ++q) {
        mx1[q] = fmaxf(mx1[q], __shfl_xor(mx1[q], off));
        mx2[q] = fmaxf(mx2[q], __shfl_xor(mx2[q], off));
      }
    float z1[4] = {0, 0, 0, 0}, z2[4] = {0, 0, 0, 0};
    #pragma unroll
    for (int t = 0; t < 14; ++t)
      #pragma unroll
      for (int q = 0; q < 4; ++q) {
        float p1 = __expf(s1[t][q] - mx1[q]);
        float p2 = __expf(s2[t][q] - mx2[q]);
        s1[t][q] = p1; s2[t][q] = p2;
        z1[q] += p1; z2[q] += p2;
      }
    #pragma unroll
    for (int off = 8; off; off >>= 1)
      #pragma unroll
      for (int q = 0; q < 4; ++q) {
        z1[q] += __shfl_xor(z1[q], off);
        z2[q] += __shfl_xor(z2[q], off);
      }
    float r1[4], r2[4];
    #pragma unroll
    for (int q = 0; q < 4; ++q) { r1[q] = 1.f / z1[q]; r2[q] = lam / z2[q]; }

    #pragma unroll
    for (int t = 0; t < 14; ++t)
      #pragma unroll
      for (int q = 0; q < 4; ++q) {
        float pc = s1[t][q] * r1[q] - s2[t][q] * r2[q];
        Pw[(g * 4 + q) * VSTR + t * 16 + l] = f2bf(pc);
      }

    fx4 o[4] = {};
    #pragma unroll
    for (int mt = 0; mt < 7; ++mt) {
      bf16x8 pa = *(const bf16x8*)(Pw + l * VSTR + mt * 32 + g * 8);
      #pragma unroll
      for (int j = 0; j < 4; ++j) {
        bf16x8 vb = *(const bf16x8*)(Vt + (j * 16 + l) * VSTR + mt * 32 + g * 8);
        o[j] = __builtin_amdgcn_mfma_f32_16x16x32_bf16(pa, vb, o[j], 0, 0, 0);
      }
    }

    float ms[4] = {0, 0, 0, 0};
    #pragma unroll
    for (int j = 0; j < 4; ++j)
      #pragma unroll
      for (int q = 0; q < 4; ++q) ms[q] += o[j][q] * o[j][q];
    #pragma unroll
    for (int off = 8; off; off >>= 1)
      #pragma unroll
      for (int q = 0; q < 4; ++q) ms[q] += __shfl_xor(ms[q], off);
    float rr[4];
    #pragma unroll
    for (int q = 0; q < 4; ++q) rr[q] = rsqrtf(ms[q] * (1.f / 64.f) + 1e-5f) * oscale;
    #pragma unroll
    for (int j = 0; j < 4; ++j) {
      float slv = sls[j * 16 + l];
      #pragma unroll
      for (int q = 0; q < 4; ++q) {
        int row = qbase + g * 4 + q;
        if (row < 197)
          outp[(size_t)(b * 197 + row) * 768 + hh * 64 + j * 16 + l] = f2bf(o[j][q] * rr[q] * slv);
      }
    }
  }
}

// per-layer weight prep: f32 [K][N] -> bf16 [N][K] via 64x64 LDS tiles; +lambda
// (R14 scalar version -- R15's vectorized rewrite regressed and was reverted)
__global__ __launch_bounds__(256)
void prep_weights(const float* __restrict__ qw, const float* __restrict__ kw,
                  const float* __restrict__ vw, const float* __restrict__ ow,
                  const float* __restrict__ w1, const float* __restrict__ w2,
                  u16* __restrict__ qkvt, u16* __restrict__ ot,
                  u16* __restrict__ w1t, u16* __restrict__ w2t,
                  const float* __restrict__ lq1, const float* __restrict__ lk1,
                  const float* __restrict__ lq2, const float* __restrict__ lk2,
                  float* __restrict__ lam_out, float lam_init)
{
  int bid = blockIdx.x;
  if (bid == 1728) {
    if (threadIdx.x < 64) {
      int lane = threadIdx.x;
      float p1 = lane < 32 ? lq1[lane] * lk1[lane] : 0.f;
      float p2 = lane < 32 ? lq2[lane] * lk2[lane] : 0.f;
      #pragma unroll
      for (int off = 32; off; off >>= 1) { p1 += __shfl_xor(p1, off); p2 += __shfl_xor(p2, off); }
      if (lane == 0) lam_out[0] = __expf(p1) - __expf(p2) + lam_init;
    }
    return;
  }
  const float* src; u16* dst; int Kd, Nd, tx, ty;
  if (bid < 576) {
    int which = bid / 144, t = bid % 144;
    ty = t / 12; tx = t % 12; Kd = 768; Nd = 768;
    src = (which == 0) ? qw : (which == 1) ? kw : (which == 2) ? vw : ow;
    dst = (which < 3) ? (qkvt + (size_t)which * 768 * 768) : ot;
  } else if (bid < 1152) {
    int t = bid - 576; ty = t / 12; tx = t % 12; Kd = 768; Nd = 3072; src = w1; dst = w1t;
  } else {
    int t = bid - 1152; ty = t / 48; tx = t % 48; Kd = 3072; Nd = 768; src = w2; dst = w2t;
  }
  __shared__ u16 tile[64][65];
  int tid2 = threadIdx.x;
  int k0 = tx * 64, n0 = ty * 64;
  #pragma unroll
  for (int j = 0; j < 16; ++j) {
    int idx = j * 256 + tid2;
    int rr = idx >> 6, cc = idx & 63;
    tile[rr][cc] = f2bf(src[(size_t)(k0 + rr) * Nd + n0 + cc]);
  }
  __syncthreads();
  #pragma unroll
  for (int j = 0; j < 16; ++j) {
    int idx = j * 256 + tid2;
    int rr = idx >> 6, cc = idx & 63;
    dst[(size_t)(n0 + rr) * Kd + k0 + cc] = tile[cc][rr];
  }
}

__global__ void convert_cw(const float* __restrict__ src, u16* __restrict__ dst)
{
  int i4 = blockIdx.x * 256 + threadIdx.x;
  fx4 v = *(const fx4*)(src + (size_t)i4 * 4);
  u16x4 o;
  #pragma unroll
  for (int e = 0; e < 4; ++e) o[e] = f2bf(v[e]);
  *(u16x4*)(dst + (size_t)i4 * 4) = o;
}

__global__ void im2col(const float* __restrict__ x, u16* __restrict__ A0)
{
  int i4 = blockIdx.x * 256 + threadIdx.x;
  int base = i4 * 4;
  int r = base / 768, c0 = base % 768;
  int b = r / 196, p = r % 196;
  int py = p / 14, px = p % 14;
  int ch = c0 >> 8;
  int cc = c0 & 255;
  int iy = cc >> 4, ix = cc & 15;
  const float* src = x + (((size_t)(b * 3 + ch) * 224 + py * 16 + iy) * 224 + px * 16 + ix);
  fx4 v = *(const fx4*)src;
  u16x4 o;
  #pragma unroll
  for (int e = 0; e < 4; ++e) o[e] = f2bf(v[e]);
  *(u16x4*)(A0 + base) = o;
}

__global__ void assemble(const float* __restrict__ tmp, const float* __restrict__ conv_b,
                         const float* __restrict__ cls, const float* __restrict__ pos,
                         float* __restrict__ h)
{
  int i4 = blockIdx.x * 256 + threadIdx.x;
  int base = i4 * 4;
  int r = base / 768, d = base % 768;
  int b = r / 197, n = r % 197;
  fx4 pv = *(const fx4*)(pos + (size_t)n * 768 + d);
  fx4 v;
  if (n == 0) {
    v = *(const fx4*)(cls + d);
  } else {
    v = *(const fx4*)(tmp + (size_t)(b * 196 + n - 1) * 768 + d);
    fx4 cb = *(const fx4*)(conv_b + d);
    v = v + cb;
  }
  *(fx4*)(h + (size_t)r * 768 + d) = v + pv;
}

// grid (32, 16); 4 waves split d into 192-chunks, LDS reduce.
__global__ __launch_bounds__(256)
void head_kernel(const float* __restrict__ ln, const float* __restrict__ hw,
                 const float* __restrict__ hb, float* __restrict__ outp)
{
  __shared__ float partial[3][64];
  int r = blockIdx.x;
  int lane = threadIdx.x & 63;
  int w = threadIdx.x >> 6;
  int c = blockIdx.y * 64 + lane;
  const float* lr = ln + (size_t)r * 768;
  float acc = 0.f;
  if (c < 1000) {
    const float* hp = hw + (size_t)(w * 192) * 1000 + c;
    #pragma unroll 4
    for (int d = 0; d < 192; ++d)
      acc = fmaf(lr[w * 192 + d], hp[(size_t)d * 1000], acc);
  }
  if (w) partial[w - 1][lane] = acc;
  __syncthreads();
  if (w == 0 && c < 1000) {
    acc += partial[0][lane] + partial[1][lane] + partial[2][lane];
    outp[r * 1000 + c] = acc + hb[c];
  }
}

extern "C" void kernel_launch(void* const* d_in, const int* in_sizes, int n_in,
                              void* d_out, int out_size, void* d_ws, size_t ws_size,
                              hipStream_t stream)
{
  (void)in_sizes; (void)n_in; (void)out_size; (void)ws_size;
  const float* x      = (const float*)d_in[0];
  const float* conv_w = (const float*)d_in[1];
  const float* conv_b = (const float*)d_in[2];
  const float* cls    = (const float*)d_in[3];
  const float* pos    = (const float*)d_in[4];
  const float* ln1_s  = (const float*)d_in[5];
  const float* ln1_b  = (const float*)d_in[6];
  const float* q_w    = (const float*)d_in[7];
  const float* k_w    = (const float*)d_in[8];
  const float* v_w    = (const float*)d_in[9];
  const float* o_w    = (const float*)d_in[10];
  const float* lq1    = (const float*)d_in[11];
  const float* lk1    = (const float*)d_in[12];
  const float* lq2    = (const float*)d_in[13];
  const float* lk2    = (const float*)d_in[14];
  const float* slsx   = (const float*)d_in[15];
  const float* ln2_s  = (const float*)d_in[16];
  const float* ln2_b  = (const float*)d_in[17];
  const float* w1     = (const float*)d_in[18];
  const float* b1     = (const float*)d_in[19];
  const float* w2     = (const float*)d_in[20];
  const float* b2     = (const float*)d_in[21];
  const float* lnf_s  = (const float*)d_in[22];
  const float* lnf_b  = (const float*)d_in[23];
  const float* head_w = (const float*)d_in[24];
  const float* head_b = (const float*)d_in[25];
  float* out = (float*)d_out;

  char* ws = (char*)d_ws;
  size_t off = 0;
  auto alloc = [&](size_t bytes) { size_t p = off; off += (bytes + 255) & ~(size_t)255; return p; };
  u16*   A_bf  = (u16*)  (ws + alloc((size_t)MPAD * 768 * 2));
  u16*   big   = (u16*)  (ws + alloc((size_t)MPAD * 3072 * 2));
  float* h     = (float*)(ws + alloc((size_t)MROWS * 768 * 4));
  u16*   wqkv  = (u16*)  (ws + alloc((size_t)2304 * 768 * 2));
  u16*   wo    = (u16*)  (ws + alloc((size_t)768 * 768 * 2));
  u16*   w1t   = (u16*)  (ws + alloc((size_t)3072 * 768 * 2));
  u16*   w2t   = (u16*)  (ws + alloc((size_t)768 * 3072 * 2));
  float* lnf_o = (float*)(ws + alloc((size_t)32 * 768 * 4));
  float* lam   = (float*)(ws + alloc(256));
  float* convtmp = (float*)big;
  u16*   cwbf  = w1t;

  hipFuncSetAttribute((const void*)diff_attn,
                      hipFuncAttributeMaxDynamicSharedMemorySize, DA_LDS);

  // patch embed
  convert_cw<<<576, 256, 0, stream>>>(conv_w, cwbf);
  im2col<<<4704, 256, 0, stream>>>(x, A_bf);
  patch_gemm<<<588, 256, 0, stream>>>(A_bf, cwbf, convtmp);   // 49 * 12
  assemble<<<4728, 256, 0, stream>>>(convtmp, conv_b, cls, pos, h);

  for (int l = 0; l < 12; ++l) {
    float lam_init = 0.8f - 0.6f * expf(-0.3f * (float)l);
    prep_weights<<<1729, 256, 0, stream>>>(
        q_w + (size_t)l * 589824, k_w + (size_t)l * 589824,
        v_w + (size_t)l * 589824, o_w + (size_t)l * 589824,
        w1 + (size_t)l * 2359296, w2 + (size_t)l * 2359296,
        wqkv, wo, w1t, w2t,
        lq1 + l * 32, lk1 + l * 32, lq2 + l * 32, lk2 + l * 32,
        lam, lam_init);
    layernorm_k<false><<<1576, 256, 0, stream>>>(h, ln1_s + l * 768, ln1_b + l * 768, A_bf, MROWS, (size_t)768);
    qkv_gemm<<<1800, 256, 0, stream>>>(A_bf, wqkv, big);                 // 50 * 36 n64
    diff_attn<<<768, 256, DA_LDS, stream>>>(big, lam, slsx + l * 64, A_bf, lam_init);
    oproj_gemm<<<600, 256, 0, stream>>>(A_bf, wo, h, h);                 // 50 * 12
    layernorm_k<false><<<1576, 256, 0, stream>>>(h, ln2_s + l * 768, ln2_b + l * 768, A_bf, MROWS, (size_t)768);
    mlp1_gemm<<<2400, 256, 0, stream>>>(A_bf, w1t, b1 + l * 3072, big);  // 50 * 48 n64
    mlp2_gemm<<<600, 256, 0, stream>>>(big, w2t, b2 + l * 768, h, h);    // 50 * 12
  }

  layernorm_k<true><<<8, 256, 0, stream>>>(h, lnf_s, lnf_b, lnf_o, 32, (size_t)197 * 768);
  head_kernel<<<dim3(32, 16), 256, 0, stream>>>(lnf_o, head_w, head_b, out);
}

// Round 17
// 2881.849 us; speedup vs baseline: 1.0434x; 1.0017x over previous
//
#include <hip/hip_runtime.h>
#include <cmath>

// ---------------------------------------------------------------------------
// DiffAttn ViT forward on MI355X (gfx950). Round 16: single-variable A/B --
// R16 config (2887us) with ONLY prep_weights swapped to the vectorized
// version (float4 loads, u16x4 stores, pad-68). Resolves R15's ambiguous
// attribution (prep-vec + attn-staging were bundled; -> +87us).
// ---------------------------------------------------------------------------

typedef unsigned short u16;
typedef u16 u16x4 __attribute__((ext_vector_type(4)));
typedef u16 u16x8 __attribute__((ext_vector_type(8)));
typedef float fx4 __attribute__((ext_vector_type(4)));
typedef __bf16 bf16x8 __attribute__((ext_vector_type(8)));

#define MROWS 6304   // B*N = 32*197
#define MPAD  6400

#define WAITV(N) asm volatile("s_waitcnt vmcnt(" #N ")" ::: "memory")

__device__ __forceinline__ float bf2f(u16 u) {
  union { unsigned int i; float f; } c; c.i = ((unsigned int)u) << 16; return c.f;
}
__device__ __forceinline__ u16 f2bf(float f) {
  union { float f; unsigned int i; } c; c.f = f;
  return (u16)((c.i + 0x7FFFu + ((c.i >> 16) & 1u)) >> 16);
}
__device__ __forceinline__ float gelu_f(float x) {
  float u = 0.7978845608028654f * (x + 0.044715f * x * x * x);
  u = fminf(fmaxf(u, -30.f), 30.f);
  float e = __expf(2.f * u);
  return 0.5f * x * (1.f + (e - 1.f) / (e + 1.f));
}

__device__ __forceinline__ void gload16(const void* g, void* l) {
  __builtin_amdgcn_global_load_lds(
      (const __attribute__((address_space(1))) void*)g,
      (__attribute__((address_space(3))) void*)l, 16, 0, 0);
}

// bijective XCD swizzle (m204)
__device__ __forceinline__ int xcd_swz(int orig, int nwg) {
  int q = nwg >> 3, r = nwg & 7;
  int x = orig & 7, i = orig >> 3;
  return (x < r ? x * (q + 1) : r * (q + 1) + (x - r) * q) + i;
}

enum { EP_F32 = 0, EP_BF16 = 1, EP_GELU_BF16 = 2, EP_RESID_F32 = 3 };

template<int MODE>
__device__ __forceinline__ void ep_store(void* outp, const float* __restrict__ resid,
                                         size_t m, size_t n, size_t N, float v) {
  if (MODE == EP_GELU_BF16)      ((u16*)outp)[m * N + n] = f2bf(gelu_f(v));
  else if (MODE == EP_BF16)      ((u16*)outp)[m * N + n] = f2bf(v);
  else if (MODE == EP_RESID_F32) ((float*)outp)[m * N + n] = resid[m * N + n] + v;
  else                           ((float*)outp)[m * N + n] = v;
}

// ---------------------------------------------------------------------------
// SMALL-N GEMM body: 128x64 tile, BK=64, 4 waves, 2-phase dbuf (STATIC 48KB,
// 3 blocks/CU), counted-vmcnt(6). Session-best family.
// ---------------------------------------------------------------------------
template<int MODE, bool BIAS>
__device__ __forceinline__
void gemm_n64_body(const u16* __restrict__ A, const u16* __restrict__ Bt,
                   const float* __restrict__ bias, const float* __restrict__ resid,
                   void* __restrict__ outp, int M, int N, int K, int NT)
{
  __shared__ unsigned char lds[2][(128 + 64) * 64 * 2];  // 48 KB
  const int tid = threadIdx.x;
  const int lane = tid & 63, w = tid >> 6;
  const int g = lane >> 4, l = lane & 15;
  const int wg = xcd_swz(blockIdx.x, gridDim.x);
  const int bm = (wg / NT) * 128, bn = (wg % NT) * 64;

  const int swz_half = ((lane & 7) ^ ((lane >> 3) & 7)) << 3;
  const u16* gA = A + (size_t)(bm + 32 * w + (lane >> 3)) * K + swz_half;
  const u16* gB = Bt + (size_t)(bn + 16 * w + (lane >> 3)) * K + swz_half;

  fx4 acc[2][4] = {};

  auto STAGE = [&](int buf, int kt) {
    unsigned char* bA = &lds[buf][0] + 4096 * w;
    unsigned char* bB = &lds[buf][0] + 16384 + 2048 * w;
    #pragma unroll
    for (int c = 0; c < 4; ++c)
      gload16(gA + (size_t)(8 * c) * K + kt, bA + (8 * c) * 128);
    #pragma unroll
    for (int c = 0; c < 2; ++c)
      gload16(gB + (size_t)(8 * c) * K + kt, bB + (8 * c) * 128);
  };

  STAGE(0, 0);
  int cur = 0;
  for (int kt = 0; kt < K; kt += 64) {
    if (kt + 64 < K) {
      STAGE(cur ^ 1, kt + 64);
      WAITV(6);
    } else {
      WAITV(0);
    }
    __builtin_amdgcn_s_barrier();
    __builtin_amdgcn_sched_barrier(0);
    const unsigned char* As = &lds[cur][0];
    const unsigned char* Bs = As + 16384;
    #pragma unroll
    for (int kk = 0; kk < 2; ++kk) {
      bf16x8 af[2], bfr[4];
      #pragma unroll
      for (int i = 0; i < 2; ++i) {
        int ar = w * 32 + i * 16 + l;
        af[i] = *(const bf16x8*)(As + ar * 128 + ((kk * 64 + g * 16) ^ ((ar & 7) << 4)));
      }
      #pragma unroll
      for (int j = 0; j < 4; ++j) {
        int br = j * 16 + l;
        bfr[j] = *(const bf16x8*)(Bs + br * 128 + ((kk * 64 + g * 16) ^ ((br & 7) << 4)));
      }
      #pragma unroll
      for (int i = 0; i < 2; ++i)
        #pragma unroll
        for (int j = 0; j < 4; ++j)
          acc[i][j] = __builtin_amdgcn_mfma_f32_16x16x32_bf16(af[i], bfr[j], acc[i][j], 0, 0, 0);
    }
    __builtin_amdgcn_sched_barrier(0);
    __builtin_amdgcn_s_barrier();
    cur ^= 1;
  }
  #pragma unroll
  for (int j = 0; j < 4; ++j) {
    int n = bn + j * 16 + l;
    float bv = BIAS ? bias[n] : 0.f;
    #pragma unroll
    for (int i = 0; i < 2; ++i) {
      int mbase = bm + w * 32 + i * 16 + g * 4;
      #pragma unroll
      for (int q = 0; q < 4; ++q) {
        int m = mbase + q;
        if (m < M) ep_store<MODE>(outp, resid, m, n, N, acc[i][j][q] + bv);
      }
    }
  }
}

// ---- kernel symbols ----
__global__ __launch_bounds__(256) void patch_gemm(const u16* A, const u16* Bt, float* outp) {
  gemm_n64_body<EP_F32, false>(A, Bt, nullptr, nullptr, outp, 6272, 768, 768, 12);
}
__global__ __launch_bounds__(256) void qkv_gemm(const u16* A, const u16* Bt, u16* outp) {
  gemm_n64_body<EP_BF16, false>(A, Bt, nullptr, nullptr, outp, MROWS, 2304, 768, 36);
}
__global__ __launch_bounds__(256) void oproj_gemm(const u16* A, const u16* Bt,
                                                  const float* resid, float* outp) {
  gemm_n64_body<EP_RESID_F32, false>(A, Bt, nullptr, resid, outp, MROWS, 768, 768, 12);
}
__global__ __launch_bounds__(256) void mlp1_gemm(const u16* A, const u16* Bt,
                                                 const float* bias, u16* outp) {
  gemm_n64_body<EP_GELU_BF16, true>(A, Bt, bias, nullptr, outp, MROWS, 3072, 768, 48);
}
__global__ __launch_bounds__(256) void mlp2_gemm(const u16* A, const u16* Bt,
                                                 const float* bias, const float* resid,
                                                 float* outp) {
  gemm_n64_body<EP_RESID_F32, true>(A, Bt, bias, resid, outp, MROWS, 768, 3072, 12);
}

// 4 rows/block (one wave each); OUTF32 ? f32 out : bf16 out
template<bool OUTF32>
__global__ __launch_bounds__(256)
void layernorm_k(const float* __restrict__ x, const float* __restrict__ s,
                 const float* __restrict__ b, void* __restrict__ outp,
                 int nrows, size_t in_rstride)
{
  int r = blockIdx.x * 4 + (threadIdx.x >> 6);
  if (r >= nrows) return;
  int lane = threadIdx.x & 63;
  const fx4* xp = (const fx4*)(x + (size_t)r * in_rstride);
  fx4 v[3];
  float sum = 0.f, sq = 0.f;
  #pragma unroll
  for (int j = 0; j < 3; ++j) {
    v[j] = xp[j * 64 + lane];
    #pragma unroll
    for (int e = 0; e < 4; ++e) { sum += v[j][e]; sq += v[j][e] * v[j][e]; }
  }
  #pragma unroll
  for (int off = 32; off; off >>= 1) { sum += __shfl_xor(sum, off); sq += __shfl_xor(sq, off); }
  float mu = sum * (1.f / 768.f);
  float var = sq * (1.f / 768.f) - mu * mu;
  float rs = rsqrtf(var + 1e-5f);
  const fx4* sp = (const fx4*)s;
  const fx4* bp = (const fx4*)b;
  #pragma unroll
  for (int j = 0; j < 3; ++j) {
    fx4 sv = sp[j * 64 + lane], bv = bp[j * 64 + lane];
    if (OUTF32) {
      fx4 o;
      #pragma unroll
      for (int e = 0; e < 4; ++e) o[e] = (v[j][e] - mu) * rs * sv[e] + bv[e];
      *(fx4*)((float*)outp + (size_t)r * 768 + (j * 64 + lane) * 4) = o;
    } else {
      u16x4 o;
      #pragma unroll
      for (int e = 0; e < 4; ++e) o[e] = f2bf((v[j][e] - mu) * rs * sv[e] + bv[e]);
      *(u16x4*)((u16*)outp + (size_t)r * 768 + (j * 64 + lane) * 4) = o;
    }
  }
}

// ---------------------------------------------------------------------------
// MFMA differential attention. One block per (batch, value-head, q-half).
// R14/R16 staging (tid<197 row-per-thread) -- measured best.
// ---------------------------------------------------------------------------
#define KSTR 40
#define VSTR 232
#define DA_LDS (2 * 224 * KSTR * 2 + 64 * VSTR * 2 + 4 * 16 * VSTR * 2)  // 95232 B

__global__ __launch_bounds__(256)
void diff_attn(const u16* __restrict__ qkv, const float* __restrict__ lam_p,
               const float* __restrict__ sls, u16* __restrict__ outp, float lam_init)
{
  extern __shared__ char smem[];
  u16* K1s = (u16*)smem;
  u16* K2s = K1s + 224 * KSTR;
  u16* Vt  = K2s + 224 * KSTR;
  const int tid = threadIdx.x;
  const int w = tid >> 6, lane = tid & 63;
  const int g = lane >> 4, l = lane & 15;
  u16* Pw = Vt + 64 * VSTR + w * 16 * VSTR;

  const int bh = blockIdx.x >> 1;
  const int half = blockIdx.x & 1;
  const int b = bh / 12, hh = bh % 12;
  const u16* base = qkv + (size_t)b * 197 * 2304;

  if (tid < 197) {
    const u16* kr = base + (size_t)tid * 2304 + 768 + hh * 64;
    *(u16x8*)(K1s + tid * KSTR + 0)  = *(const u16x8*)(kr + 0);
    *(u16x8*)(K1s + tid * KSTR + 8)  = *(const u16x8*)(kr + 8);
    *(u16x8*)(K1s + tid * KSTR + 16) = *(const u16x8*)(kr + 16);
    *(u16x8*)(K1s + tid * KSTR + 24) = *(const u16x8*)(kr + 24);
    *(u16x8*)(K2s + tid * KSTR + 0)  = *(const u16x8*)(kr + 32);
    *(u16x8*)(K2s + tid * KSTR + 8)  = *(const u16x8*)(kr + 40);
    *(u16x8*)(K2s + tid * KSTR + 16) = *(const u16x8*)(kr + 48);
    *(u16x8*)(K2s + tid * KSTR + 24) = *(const u16x8*)(kr + 56);
    const u16* vr = base + (size_t)tid * 2304 + 1536 + hh * 64;
    #pragma unroll
    for (int jj = 0; jj < 8; ++jj) {
      u16x8 vv = *(const u16x8*)(vr + jj * 8);
      #pragma unroll
      for (int e = 0; e < 8; ++e) Vt[(jj * 8 + e) * VSTR + tid] = vv[e];
    }
  }
  for (int idx = tid; idx < 64 * 27; idx += 256) {
    Vt[(idx / 27) * VSTR + 197 + (idx % 27)] = 0;
  }
  __syncthreads();

  const float lam = lam_p[0];
  const float oscale = 1.f - lam_init;
  const float scale = 0.17677669529663687f;
  const fx4 zero = {};

  const int qb_lo = half ? 7 : 0;
  const int qb_hi = half ? 13 : 7;
  for (int qb = qb_lo + w; qb < qb_hi; qb += 4) {
    const int qbase = qb * 16;
    const u16* qrow = base + (size_t)(qbase + l) * 2304 + hh * 64;
    bf16x8 qf1 = *(const bf16x8*)(qrow + g * 8);
    bf16x8 qf2 = *(const bf16x8*)(qrow + 32 + g * 8);

    fx4 s1[14], s2[14];
    #pragma unroll
    for (int t = 0; t < 14; ++t) {
      bf16x8 kf1 = *(const bf16x8*)(K1s + (t * 16 + l) * KSTR + g * 8);
      bf16x8 kf2 = *(const bf16x8*)(K2s + (t * 16 + l) * KSTR + g * 8);
      s1[t] = __builtin_amdgcn_mfma_f32_16x16x32_bf16(qf1, kf1, zero, 0, 0, 0);
      s2[t] = __builtin_amdgcn_mfma_f32_16x16x32_bf16(qf2, kf2, zero, 0, 0, 0);
    }

    float mx1[4] = {-1e30f, -1e30f, -1e30f, -1e30f};
    float mx2[4] = {-1e30f, -1e30f, -1e30f, -1e30f};
    #pragma unroll
    for (int t = 0; t < 14; ++t) {
      bool ok = (t * 16 + l) < 197;
      #pragma unroll
      for (int q = 0; q < 4; ++q) {
        float v1 = ok ? s1[t][q] * scale : -1e30f;
        float v2 = ok ? s2[t][q] * scale : -1e30f;
        s1[t][q] = v1; s2[t][q] = v2;
        mx1[q] = fmaxf(mx1[q], v1); mx2[q] = fmaxf(mx2[q], v2);
      }
    }
    #pragma unroll
    for (int off = 8; off; off >>= 1)
      #pragma unroll
      for (int q = 0; q < 4; ++q) {
        mx1[q] = fmaxf(mx1[q], __shfl_xor(mx1[q], off));
        mx2[q] = fmaxf(mx2[q], __shfl_xor(mx2[q], off));
      }
    float z1[4] = {0, 0, 0, 0}, z2[4] = {0, 0, 0, 0};
    #pragma unroll
    for (int t = 0; t < 14; ++t)
      #pragma unroll
      for (int q = 0; q < 4; ++q) {
        float p1 = __expf(s1[t][q] - mx1[q]);
        float p2 = __expf(s2[t][q] - mx2[q]);
        s1[t][q] = p1; s2[t][q] = p2;
        z1[q] += p1; z2[q] += p2;
      }
    #pragma unroll
    for (int off = 8; off; off >>= 1)
      #pragma unroll
      for (int q = 0; q < 4; ++q) {
        z1[q] += __shfl_xor(z1[q], off);
        z2[q] += __shfl_xor(z2[q], off);
      }
    float r1[4], r2[4];
    #pragma unroll
    for (int q = 0; q < 4; ++q) { r1[q] = 1.f / z1[q]; r2[q] = lam / z2[q]; }

    #pragma unroll
    for (int t = 0; t < 14; ++t)
      #pragma unroll
      for (int q = 0; q < 4; ++q) {
        float pc = s1[t][q] * r1[q] - s2[t][q] * r2[q];
        Pw[(g * 4 + q) * VSTR + t * 16 + l] = f2bf(pc);
      }

    fx4 o[4] = {};
    #pragma unroll
    for (int mt = 0; mt < 7; ++mt) {
      bf16x8 pa = *(const bf16x8*)(Pw + l * VSTR + mt * 32 + g * 8);
      #pragma unroll
      for (int j = 0; j < 4; ++j) {
        bf16x8 vb = *(const bf16x8*)(Vt + (j * 16 + l) * VSTR + mt * 32 + g * 8);
        o[j] = __builtin_amdgcn_mfma_f32_16x16x32_bf16(pa, vb, o[j], 0, 0, 0);
      }
    }

    float ms[4] = {0, 0, 0, 0};
    #pragma unroll
    for (int j = 0; j < 4; ++j)
      #pragma unroll
      for (int q = 0; q < 4; ++q) ms[q] += o[j][q] * o[j][q];
    #pragma unroll
    for (int off = 8; off; off >>= 1)
      #pragma unroll
      for (int q = 0; q < 4; ++q) ms[q] += __shfl_xor(ms[q], off);
    float rr[4];
    #pragma unroll
    for (int q = 0; q < 4; ++q) rr[q] = rsqrtf(ms[q] * (1.f / 64.f) + 1e-5f) * oscale;
    #pragma unroll
    for (int j = 0; j < 4; ++j) {
      float slv = sls[j * 16 + l];
      #pragma unroll
      for (int q = 0; q < 4; ++q) {
        int row = qbase + g * 4 + q;
        if (row < 197)
          outp[(size_t)(b * 197 + row) * 768 + hh * 64 + j * 16 + l] = f2bf(o[j][q] * rr[q] * slv);
      }
    }
  }
}

// per-layer weight prep: f32 [K][N] -> bf16 [N][K]; VECTORIZED (float4 in,
// u16x4 out); tile pad 68 -> 8B-aligned rows; transpose-read banks verified
// conflict-free (row stride 136B = 2-bank step, 16 lanes -> 16 banks).
__global__ __launch_bounds__(256)
void prep_weights(const float* __restrict__ qw, const float* __restrict__ kw,
                  const float* __restrict__ vw, const float* __restrict__ ow,
                  const float* __restrict__ w1, const float* __restrict__ w2,
                  u16* __restrict__ qkvt, u16* __restrict__ ot,
                  u16* __restrict__ w1t, u16* __restrict__ w2t,
                  const float* __restrict__ lq1, const float* __restrict__ lk1,
                  const float* __restrict__ lq2, const float* __restrict__ lk2,
                  float* __restrict__ lam_out, float lam_init)
{
  int bid = blockIdx.x;
  if (bid == 1728) {
    if (threadIdx.x < 64) {
      int lane = threadIdx.x;
      float p1 = lane < 32 ? lq1[lane] * lk1[lane] : 0.f;
      float p2 = lane < 32 ? lq2[lane] * lk2[lane] : 0.f;
      #pragma unroll
      for (int off = 32; off; off >>= 1) { p1 += __shfl_xor(p1, off); p2 += __shfl_xor(p2, off); }
      if (lane == 0) lam_out[0] = __expf(p1) - __expf(p2) + lam_init;
    }
    return;
  }
  const float* src; u16* dst; int Kd, Nd, tx, ty;
  if (bid < 576) {
    int which = bid / 144, t = bid % 144;
    ty = t / 12; tx = t % 12; Kd = 768; Nd = 768;
    src = (which == 0) ? qw : (which == 1) ? kw : (which == 2) ? vw : ow;
    dst = (which < 3) ? (qkvt + (size_t)which * 768 * 768) : ot;
  } else if (bid < 1152) {
    int t = bid - 576; ty = t / 12; tx = t % 12; Kd = 768; Nd = 3072; src = w1; dst = w1t;
  } else {
    int t = bid - 1152; ty = t / 48; tx = t % 48; Kd = 3072; Nd = 768; src = w2; dst = w2t;
  }
  __shared__ u16 tile[64][68];
  int tid2 = threadIdx.x;
  int k0 = tx * 64, n0 = ty * 64;
  #pragma unroll
  for (int j = 0; j < 4; ++j) {
    int idx = j * 256 + tid2;
    int rr = idx >> 4, c4 = idx & 15;
    fx4 v = *(const fx4*)(src + (size_t)(k0 + rr) * Nd + n0 + c4 * 4);
    u16x4 o;
    #pragma unroll
    for (int e = 0; e < 4; ++e) o[e] = f2bf(v[e]);
    *(u16x4*)&tile[rr][c4 * 4] = o;
  }
  __syncthreads();
  #pragma unroll
  for (int j = 0; j < 4; ++j) {
    int idx = j * 256 + tid2;
    int rr = idx >> 4, c4 = idx & 15;
    u16x4 o;
    #pragma unroll
    for (int e = 0; e < 4; ++e) o[e] = tile[c4 * 4 + e][rr];
    *(u16x4*)(dst + (size_t)(n0 + rr) * Kd + k0 + c4 * 4) = o;
  }
}

__global__ void convert_cw(const float* __restrict__ src, u16* __restrict__ dst)
{
  int i4 = blockIdx.x * 256 + threadIdx.x;
  fx4 v = *(const fx4*)(src + (size_t)i4 * 4);
  u16x4 o;
  #pragma unroll
  for (int e = 0; e < 4; ++e) o[e] = f2bf(v[e]);
  *(u16x4*)(dst + (size_t)i4 * 4) = o;
}

__global__ void im2col(const float* __restrict__ x, u16* __restrict__ A0)
{
  int i4 = blockIdx.x * 256 + threadIdx.x;
  int base = i4 * 4;
  int r = base / 768, c0 = base % 768;
  int b = r / 196, p = r % 196;
  int py = p / 14, px = p % 14;
  int ch = c0 >> 8;
  int cc = c0 & 255;
  int iy = cc >> 4, ix = cc & 15;
  const float* src = x + (((size_t)(b * 3 + ch) * 224 + py * 16 + iy) * 224 + px * 16 + ix);
  fx4 v = *(const fx4*)src;
  u16x4 o;
  #pragma unroll
  for (int e = 0; e < 4; ++e) o[e] = f2bf(v[e]);
  *(u16x4*)(A0 + base) = o;
}

__global__ void assemble(const float* __restrict__ tmp, const float* __restrict__ conv_b,
                         const float* __restrict__ cls, const float* __restrict__ pos,
                         float* __restrict__ h)
{
  int i4 = blockIdx.x * 256 + threadIdx.x;
  int base = i4 * 4;
  int r = base / 768, d = base % 768;
  int b = r / 197, n = r % 197;
  fx4 pv = *(const fx4*)(pos + (size_t)n * 768 + d);
  fx4 v;
  if (n == 0) {
    v = *(const fx4*)(cls + d);
  } else {
    v = *(const fx4*)(tmp + (size_t)(b * 196 + n - 1) * 768 + d);
    fx4 cb = *(const fx4*)(conv_b + d);
    v = v + cb;
  }
  *(fx4*)(h + (size_t)r * 768 + d) = v + pv;
}

// grid (32, 16); 4 waves split d into 192-chunks, LDS reduce.
__global__ __launch_bounds__(256)
void head_kernel(const float* __restrict__ ln, const float* __restrict__ hw,
                 const float* __restrict__ hb, float* __restrict__ outp)
{
  __shared__ float partial[3][64];
  int r = blockIdx.x;
  int lane = threadIdx.x & 63;
  int w = threadIdx.x >> 6;
  int c = blockIdx.y * 64 + lane;
  const float* lr = ln + (size_t)r * 768;
  float acc = 0.f;
  if (c < 1000) {
    const float* hp = hw + (size_t)(w * 192) * 1000 + c;
    #pragma unroll 4
    for (int d = 0; d < 192; ++d)
      acc = fmaf(lr[w * 192 + d], hp[(size_t)d * 1000], acc);
  }
  if (w) partial[w - 1][lane] = acc;
  __syncthreads();
  if (w == 0 && c < 1000) {
    acc += partial[0][lane] + partial[1][lane] + partial[2][lane];
    outp[r * 1000 + c] = acc + hb[c];
  }
}

extern "C" void kernel_launch(void* const* d_in, const int* in_sizes, int n_in,
                              void* d_out, int out_size, void* d_ws, size_t ws_size,
                              hipStream_t stream)
{
  (void)in_sizes; (void)n_in; (void)out_size; (void)ws_size;
  const float* x      = (const float*)d_in[0];
  const float* conv_w = (const float*)d_in[1];
  const float* conv_b = (const float*)d_in[2];
  const float* cls    = (const float*)d_in[3];
  const float* pos    = (const float*)d_in[4];
  const float* ln1_s  = (const float*)d_in[5];
  const float* ln1_b  = (const float*)d_in[6];
  const float* q_w    = (const float*)d_in[7];
  const float* k_w    = (const float*)d_in[8];
  const float* v_w    = (const float*)d_in[9];
  const float* o_w    = (const float*)d_in[10];
  const float* lq1    = (const float*)d_in[11];
  const float* lk1    = (const float*)d_in[12];
  const float* lq2    = (const float*)d_in[13];
  const float* lk2    = (const float*)d_in[14];
  const float* slsx   = (const float*)d_in[15];
  const float* ln2_s  = (const float*)d_in[16];
  const float* ln2_b  = (const float*)d_in[17];
  const float* w1     = (const float*)d_in[18];
  const float* b1     = (const float*)d_in[19];
  const float* w2     = (const float*)d_in[20];
  const float* b2     = (const float*)d_in[21];
  const float* lnf_s  = (const float*)d_in[22];
  const float* lnf_b  = (const float*)d_in[23];
  const float* head_w = (const float*)d_in[24];
  const float* head_b = (const float*)d_in[25];
  float* out = (float*)d_out;

  char* ws = (char*)d_ws;
  size_t off = 0;
  auto alloc = [&](size_t bytes) { size_t p = off; off += (bytes + 255) & ~(size_t)255; return p; };
  u16*   A_bf  = (u16*)  (ws + alloc((size_t)MPAD * 768 * 2));
  u16*   big   = (u16*)  (ws + alloc((size_t)MPAD * 3072 * 2));
  float* h     = (float*)(ws + alloc((size_t)MROWS * 768 * 4));
  u16*   wqkv  = (u16*)  (ws + alloc((size_t)2304 * 768 * 2));
  u16*   wo    = (u16*)  (ws + alloc((size_t)768 * 768 * 2));
  u16*   w1t   = (u16*)  (ws + alloc((size_t)3072 * 768 * 2));
  u16*   w2t   = (u16*)  (ws + alloc((size_t)768 * 3072 * 2));
  float* lnf_o = (float*)(ws + alloc((size_t)32 * 768 * 4));
  float* lam   = (float*)(ws + alloc(256));
  float* convtmp = (float*)big;
  u16*   cwbf  = w1t;

  hipFuncSetAttribute((const void*)diff_attn,
                      hipFuncAttributeMaxDynamicSharedMemorySize, DA_LDS);

  // patch embed
  convert_cw<<<576, 256, 0, stream>>>(conv_w, cwbf);
  im2col<<<4704, 256, 0, stream>>>(x, A_bf);
  patch_gemm<<<588, 256, 0, stream>>>(A_bf, cwbf, convtmp);   // 49 * 12
  assemble<<<4728, 256, 0, stream>>>(convtmp, conv_b, cls, pos, h);

  for (int l = 0; l < 12; ++l) {
    float lam_init = 0.8f - 0.6f * expf(-0.3f * (float)l);
    prep_weights<<<1729, 256, 0, stream>>>(
        q_w + (size_t)l * 589824, k_w + (size_t)l * 589824,
        v_w + (size_t)l * 589824, o_w + (size_t)l * 589824,
        w1 + (size_t)l * 2359296, w2 + (size_t)l * 2359296,
        wqkv, wo, w1t, w2t,
        lq1 + l * 32, lk1 + l * 32, lq2 + l * 32, lk2 + l * 32,
        lam, lam_init);
    layernorm_k<false><<<1576, 256, 0, stream>>>(h, ln1_s + l * 768, ln1_b + l * 768, A_bf, MROWS, (size_t)768);
    qkv_gemm<<<1800, 256, 0, stream>>>(A_bf, wqkv, big);                 // 50 * 36 n64
    diff_attn<<<768, 256, DA_LDS, stream>>>(big, lam, slsx + l * 64, A_bf, lam_init);
    oproj_gemm<<<600, 256, 0, stream>>>(A_bf, wo, h, h);                 // 50 * 12
    layernorm_k<false><<<1576, 256, 0, stream>>>(h, ln2_s + l * 768, ln2_b + l * 768, A_bf, MROWS, (size_t)768);
    mlp1_gemm<<<2400, 256, 0, stream>>>(A_bf, w1t, b1 + l * 3072, big);  // 50 * 48 n64
    mlp2_gemm<<<600, 256, 0, stream>>>(big, w2t, b2 + l * 768, h, h);    // 50 * 12
  }

  layernorm_k<true><<<8, 256, 0, stream>>>(h, lnf_s, lnf_b, lnf_o, 32, (size_t)197 * 768);
  head_kernel<<<dim3(32, 16), 256, 0, stream>>>(lnf_o, head_w, head_b, out);
}